// Round 5
// baseline (11.146 us; speedup 1.0000x reference)
//
#include <hip/hip_runtime.h>
#include <math.h>

// Problem constants (reference: B=16, C=3, H=W=512, N_BINS=100)
#define HDIM   512
#define WDIM   512
#define BATCH  16
#define NBINS  100
#define NPIX   (HDIM * WDIM)
#define BG     4            // batches per block (batch-group size)

// max_radius = sqrt(512^2+512^2)/2 = 256*sqrt(2); step = max_radius/100
#define STEP      3.6203867196751236f
#define INV_STEP  0.27621358640099516f
#define CUT       8.0f      // sigmoid(-8)=3.35e-4; truncation err <= ~7e-4 << 2e-2

__device__ __forceinline__ float2 fma2(float a, float2 m, float2 c) {
    c.x = fmaf(a, m.x, c.x);
    c.y = fmaf(a, m.y, c.y);
    return c;
}

__global__ __launch_bounds__(256) void fq_mask_kernel(
    const float* __restrict__ value_set,  // [16][100]
    float* __restrict__ out_mask,         // [16][512][512]
    float* __restrict__ out_vs)           // [16][100] passthrough
{
    // Block = (batch-group bg of 4 batches) x (16x32 pixel tile). 2048 blocks
    // -> 8192 waves -> 8 waves/SIMD (occupancy cap) for max latency hiding.
    const int bg   = blockIdx.x >> 9;     // 0..3
    const int tile = blockIdx.x & 511;    // 0..511
    const int tid  = threadIdx.x;

    // Stage this group's value rows transposed: vst[r][j] = value_set[bg*4+j][r]
    __shared__ __align__(16) float vst[NBINS * BG];
    for (int i = tid; i < NBINS * BG; i += 256) {
        int r = i >> 2, j = i & 3;
        vst[i] = value_set[(bg * BG + j) * NBINS + r];
    }
    __syncthreads();

    // Wave = 4 rows x 32 cols; thread = 2 consecutive cols (float2 stores).
    // Per-row store segment = 16 lanes x 8B = 128B full line, aligned.
    const int lane   = tid & 63;
    const int wv     = tid >> 6;
    const int row_in = wv * 4 + (lane >> 4);
    const int col_in = (lane & 15) * 2;
    const int ty = tile >> 4;             // 0..31
    const int tx = tile & 15;             // 0..15
    const int h  = ty * 16 + row_in;
    const int w  = tx * 32 + col_in;

    const float fy  = (float)h - 256.0f;
    const float dy2 = fy * fy;
    float d[2];
    #pragma unroll
    for (int p = 0; p < 2; ++p) {
        float dx = (float)(w + p) - 256.0f;
        d[p] = sqrtf(dy2 + dx * dx);
    }
    const float dmin = fminf(d[0], d[1]);
    const float dmax = fmaxf(d[0], d[1]);
    int r_lo = (int)floorf((dmin - CUT) * INV_STEP); if (r_lo < 0) r_lo = 0;
    int r_hi = (int)floorf((dmax + CUT) * INV_STEP); if (r_hi > NBINS - 1) r_hi = NBINS - 1;
    const int cnt = r_hi - r_lo + 1;   // ~5 iterations

    // e_p = exp(dist_p - STEP*(r+1)); per bin: s = 1/(1+e), then e *= exp(-STEP).
    const float dec = __expf(-STEP);
    float e[2], sp[2];
    #pragma unroll
    for (int p = 0; p < 2; ++p) {
        e[p]  = __expf(d[p] - STEP * (float)(r_lo + 1));
        sp[p] = 0.0f;   // matches reference: mask 0 = s[0] - 0
    }

    float2 acc[BG];
    #pragma unroll
    for (int j = 0; j < BG; ++j) acc[j] = make_float2(0.f, 0.f);

    const float4* vr = (const float4*)vst;
    int r = r_lo;
    for (int i = 0; i < cnt; ++i, ++r) {
        float mm[2];
        #pragma unroll
        for (int p = 0; p < 2; ++p) {
            float s = __builtin_amdgcn_rcpf(1.0f + e[p]);  // sigmoid
            mm[p]  = s - sp[p];
            sp[p]  = s;
            e[p]  *= dec;
        }
        const float2 m = make_float2(mm[0], mm[1]);
        float4 v = vr[r];    // broadcast-ish: <=3 distinct consecutive rows/wave
        acc[0] = fma2(v.x, m, acc[0]);
        acc[1] = fma2(v.y, m, acc[1]);
        acc[2] = fma2(v.z, m, acc[2]);
        acc[3] = fma2(v.w, m, acc[3]);
    }

    const int pixbase = h * WDIM + w;
    #pragma unroll
    for (int j = 0; j < BG; ++j)
        *(float2*)&out_mask[(bg * BG + j) * NPIX + pixbase] = acc[j];

    // Output 1: value_set passthrough (d_out is poisoned -> must write).
    if (blockIdx.x == 0) {
        for (int i = tid; i < BATCH * NBINS; i += 256)
            out_vs[i] = value_set[i];
    }
}

extern "C" void kernel_launch(void* const* d_in, const int* in_sizes, int n_in,
                              void* d_out, int out_size, void* d_ws, size_t ws_size,
                              hipStream_t stream) {
    // d_in[0] = x [16,3,512,512] fp32 — UNUSED by the math (shape-only).
    const float* value_set = (const float*)d_in[1];   // [16,100] fp32
    float* out_mask = (float*)d_out;                  // [16,512,512]
    float* out_vs   = (float*)d_out + BATCH * NPIX;   // [16,100]

    const int threads = 256;
    const int blocks  = (BATCH / BG) * (HDIM / 16) * (WDIM / 32);  // 4*32*16 = 2048
    fq_mask_kernel<<<blocks, threads, 0, stream>>>(value_set, out_mask, out_vs);
}